// Round 1
// baseline (3556.495 us; speedup 1.0000x reference)
//
#include <hip/hip_runtime.h>

#define B 4
#define N 16384
#define D 256
#define K 512
#define ITERS 10

// ---------------- MT19937 exactly matching CPython random.seed(42); random.sample(range(16384), 512)
__global__ void k_init_inds(int* __restrict__ inds) {
    __shared__ unsigned int mt[624];
    __shared__ unsigned char seen[N];
    for (int i = threadIdx.x; i < N; i += blockDim.x) seen[i] = 0;
    __syncthreads();
    if (threadIdx.x != 0) return;
    // init_genrand(19650218)
    mt[0] = 19650218u;
    for (int i = 1; i < 624; i++)
        mt[i] = 1812433253u * (mt[i - 1] ^ (mt[i - 1] >> 30)) + (unsigned)i;
    // init_by_array(key=[42])
    {
        int i = 1, j = 0;
        for (int kk = 624; kk; kk--) {
            mt[i] = (mt[i] ^ ((mt[i - 1] ^ (mt[i - 1] >> 30)) * 1664525u)) + 42u + (unsigned)j;
            i++; j++;
            if (i >= 624) { mt[0] = mt[623]; i = 1; }
            if (j >= 1) j = 0;
        }
        for (int kk = 623; kk; kk--) {
            mt[i] = (mt[i] ^ ((mt[i - 1] ^ (mt[i - 1] >> 30)) * 1566083941u)) - (unsigned)i;
            i++;
            if (i >= 624) { mt[0] = mt[623]; i = 1; }
        }
        mt[0] = 0x80000000u;
    }
    int mti = 624;
    int got = 0;
    while (got < K) {
        if (mti >= 624) {
            for (int kk = 0; kk < 624; kk++) {
                unsigned int yy = (mt[kk] & 0x80000000u) | (mt[(kk + 1) % 624] & 0x7fffffffu);
                mt[kk] = mt[(kk + 397) % 624] ^ (yy >> 1) ^ ((yy & 1u) ? 0x9908b0dfu : 0u);
            }
            mti = 0;
        }
        unsigned int y = mt[mti++];
        y ^= y >> 11; y ^= (y << 7) & 0x9d2c5680u; y ^= (y << 15) & 0xefc60000u; y ^= y >> 18;
        unsigned int r = y >> 17;          // getrandbits(15)
        if (r >= (unsigned)N) continue;    // _randbelow rejection
        if (seen[r]) continue;             // sample's "while j in selected" rejection
        seen[r] = 1;
        inds[got++] = (int)r;
    }
}

__global__ void k_gather_v0(const float* __restrict__ x, const int* __restrict__ inds,
                            float* __restrict__ v) {
    int bk = blockIdx.x; int b = bk / K, k = bk % K;
    int n = inds[k];
    const float4* src = (const float4*)(x + ((size_t)b * N + n) * D);
    float4* dst = (float4*)(v + ((size_t)b * K + k) * D);
    dst[threadIdx.x] = src[threadIdx.x];
}

// squared row norms; one wave per row (D=256 -> one float4 per lane)
__global__ void k_rownorm(const float* __restrict__ a, float* __restrict__ out, int nrows) {
    int wave = threadIdx.x >> 6;
    int lane = threadIdx.x & 63;
    int row = blockIdx.x * 4 + wave;
    if (row >= nrows) return;
    float4 f = ((const float4*)(a + (size_t)row * D))[lane];
    float s = f.x * f.x + f.y * f.y + f.z * f.z + f.w * f.w;
    #pragma unroll
    for (int off = 32; off; off >>= 1) s += __shfl_xor(s, off);
    if (lane == 0) out[row] = s;
}

// totsum[b][d] = sum_n x[b][n][d]  (fallback center for empty clusters: un = eps/eps = 1.0 for all n)
__global__ void k_totsum(const float* __restrict__ x, float* __restrict__ totsum) {
    int b = blockIdx.y;
    int n0 = blockIdx.x * (N / 64);
    int t = threadIdx.x;
    const float* xb = x + (size_t)b * N * D;
    float s = 0.f;
    for (int n = n0; n < n0 + N / 64; n++) s += xb[(size_t)n * D + t];
    atomicAdd(&totsum[b * D + t], s);
}

// ---------------- assignment: fused GEMM (x . v^T) + argmin of relu(x2 - 2*dot + v2)
// block: 256 threads as 16(ty=points) x 16(tx=centers); 64 points x 64-center chunks, 4x4 microtile
__global__ __launch_bounds__(256) void k_assign(
    const float* __restrict__ x, const float* __restrict__ v,
    const float* __restrict__ x2, const float* __restrict__ v2,
    int* __restrict__ assign) {
    __shared__ float xs[32 * 64];
    __shared__ float vs[32 * 64];
    int b = blockIdx.y;
    int n0 = blockIdx.x * 64;
    int tid = threadIdx.x;
    int tx = tid & 15, ty = tid >> 4;
    const float* xb = x + (size_t)b * N * D;
    const float* vb = v + (size_t)b * K * D;
    const float* v2b = v2 + b * K;
    float x2p[4];
    #pragma unroll
    for (int i = 0; i < 4; i++) x2p[i] = x2[b * N + n0 + ty * 4 + i];
    float minv[4]; int mini[4];
    #pragma unroll
    for (int i = 0; i < 4; i++) { minv[i] = 3.4e38f; mini[i] = 0; }
    int r = tid >> 2;    // row 0..63 within tile
    int q = tid & 3;     // which 8-dim group

    for (int kc = 0; kc < K / 64; kc++) {
        float acc[4][4];
        #pragma unroll
        for (int i = 0; i < 4; i++)
            #pragma unroll
            for (int j = 0; j < 4; j++) acc[i][j] = 0.f;

        for (int dc = 0; dc < D / 32; dc++) {
            const float* xsrc = xb + (size_t)(n0 + r) * D + dc * 32 + q * 8;
            float4 a0 = ((const float4*)xsrc)[0];
            float4 a1 = ((const float4*)xsrc)[1];
            const float* vsrc = vb + (size_t)(kc * 64 + r) * D + dc * 32 + q * 8;
            float4 b0 = ((const float4*)vsrc)[0];
            float4 b1 = ((const float4*)vsrc)[1];
            int c0 = q * 8;
            xs[(c0 + 0) * 64 + r] = a0.x; xs[(c0 + 1) * 64 + r] = a0.y;
            xs[(c0 + 2) * 64 + r] = a0.z; xs[(c0 + 3) * 64 + r] = a0.w;
            xs[(c0 + 4) * 64 + r] = a1.x; xs[(c0 + 5) * 64 + r] = a1.y;
            xs[(c0 + 6) * 64 + r] = a1.z; xs[(c0 + 7) * 64 + r] = a1.w;
            vs[(c0 + 0) * 64 + r] = b0.x; vs[(c0 + 1) * 64 + r] = b0.y;
            vs[(c0 + 2) * 64 + r] = b0.z; vs[(c0 + 3) * 64 + r] = b0.w;
            vs[(c0 + 4) * 64 + r] = b1.x; vs[(c0 + 5) * 64 + r] = b1.y;
            vs[(c0 + 6) * 64 + r] = b1.z; vs[(c0 + 7) * 64 + r] = b1.w;
            __syncthreads();
            #pragma unroll
            for (int d = 0; d < 32; d++) {
                float4 xf = *(const float4*)&xs[d * 64 + ty * 4];
                float4 vf = *(const float4*)&vs[d * 64 + tx * 4];
                float xa[4] = {xf.x, xf.y, xf.z, xf.w};
                float va[4] = {vf.x, vf.y, vf.z, vf.w};
                #pragma unroll
                for (int i = 0; i < 4; i++)
                    #pragma unroll
                    for (int j = 0; j < 4; j++)
                        acc[i][j] = fmaf(xa[i], va[j], acc[i][j]);
            }
            __syncthreads();
        }
        #pragma unroll
        for (int j = 0; j < 4; j++) {
            int kk = kc * 64 + tx * 4 + j;
            float v2v = v2b[kk];
            #pragma unroll
            for (int i = 0; i < 4; i++) {
                float dist = (x2p[i] - 2.0f * acc[i][j]) + v2v;  // match ref expression order
                dist = fmaxf(dist, 0.0f);                        // relu
                if (dist < minv[i]) { minv[i] = dist; mini[i] = kk; }
            }
        }
    }
    // reduce (min, first-index) across the 16 tx lanes (consecutive lanes in-wave)
    #pragma unroll
    for (int i = 0; i < 4; i++) {
        float mv = minv[i]; int mi = mini[i];
        #pragma unroll
        for (int off = 1; off < 16; off <<= 1) {
            float ov = __shfl_xor(mv, off);
            int oi = __shfl_xor(mi, off);
            if (ov < mv || (ov == mv && oi < mi)) { mv = ov; mi = oi; }
        }
        if (tx == 0) assign[b * N + n0 + ty * 4 + i] = mi;
    }
}

__global__ void k_count(const int* __restrict__ assign, int* __restrict__ counts) {
    int idx = blockIdx.x * 256 + threadIdx.x;
    int b = idx / N;
    int a = assign[idx];
    atomicAdd(&counts[b * K + a], 1);
}

// counting-sort scatter: block = 256 consecutive points of one batch
__global__ __launch_bounds__(256) void k_scatter(
    const int* __restrict__ assign, const int* __restrict__ counts,
    int* __restrict__ cursor, int* __restrict__ order) {
    __shared__ int offs[K];
    int b = blockIdx.y;
    if (threadIdx.x < 64) {       // wave 0 computes exclusive prefix of counts[b][*]
        int lane = threadIdx.x;
        int pre[8]; int s = 0;
        #pragma unroll
        for (int j = 0; j < 8; j++) { pre[j] = s; s += counts[b * K + lane * 8 + j]; }
        int inc = s;
        #pragma unroll
        for (int off = 1; off < 64; off <<= 1) {
            int o = __shfl_up(inc, off);
            if (lane >= off) inc += o;
        }
        int excl = inc - s;
        #pragma unroll
        for (int j = 0; j < 8; j++) offs[lane * 8 + j] = excl + pre[j];
    }
    __syncthreads();
    int n = blockIdx.x * 256 + threadIdx.x;
    int a = assign[b * N + n];
    int pos = atomicAdd(&cursor[b * K + a], 1);
    order[b * N + offs[a] + pos] = n;
}

// per-(b,k): mean of member rows; empty cluster -> totsum row. thread t <-> dim t (D==256==blockDim)
__global__ __launch_bounds__(256) void k_sumdiv(
    const float* __restrict__ x, const int* __restrict__ counts,
    const int* __restrict__ order, const float* __restrict__ totsum,
    float* __restrict__ v) {
    __shared__ int sh[256];
    __shared__ int ord[256];
    int t = threadIdx.x;
    int b = blockIdx.y, k = blockIdx.x;
    const int* cb = counts + b * K;
    int partial = 0;
    for (int j = t; j < k; j += 256) partial += cb[j];
    sh[t] = partial; __syncthreads();
    for (int s = 128; s; s >>= 1) { if (t < s) sh[t] += sh[t + s]; __syncthreads(); }
    int off = sh[0];
    int cnt = cb[k];
    const float* xb = x + (size_t)b * N * D;
    float acc = 0.f;
    for (int m0 = 0; m0 < cnt; m0 += 256) {
        int mm = min(256, cnt - m0);
        if (t < mm) ord[t] = order[b * N + off + m0 + t];
        __syncthreads();
        for (int m = 0; m < mm; m++) {
            int n = ord[m];
            acc += xb[(size_t)n * D + t];
        }
        __syncthreads();
    }
    float out;
    if (cnt > 0) out = acc * (1.0f / (float)cnt);   // un_member = (1+eps)/(cnt+eps) == 1/cnt in fp32
    else out = totsum[b * D + t];                   // un = eps/eps = 1.0 for all n
    v[((size_t)b * K + k) * D + t] = out;
}

__global__ void k_write_u(const int* __restrict__ assign, float* __restrict__ uout) {
    int idx = blockIdx.x * 256 + threadIdx.x;
    int a = assign[idx];
    uout[(size_t)idx * K + a] = 1.0f;
}

__global__ void k_copy_v(const float* __restrict__ v, float* __restrict__ out) {
    int idx = blockIdx.x * 256 + threadIdx.x;
    ((float4*)out)[idx] = ((const float4*)v)[idx];
}

extern "C" void kernel_launch(void* const* d_in, const int* in_sizes, int n_in,
                              void* d_out, int out_size, void* d_ws, size_t ws_size,
                              hipStream_t stream) {
    const float* x = (const float*)d_in[0];
    float* out = (float*)d_out;
    char* ws = (char*)d_ws;
    size_t off = 0;
    float* v      = (float*)(ws + off); off += (size_t)B * K * D * 4;
    float* x2     = (float*)(ws + off); off += (size_t)B * N * 4;
    float* v2     = (float*)(ws + off); off += (size_t)B * K * 4;
    float* totsum = (float*)(ws + off); off += (size_t)B * D * 4;
    int* assign   = (int*)(ws + off);   off += (size_t)B * N * 4;
    int* counts   = (int*)(ws + off);   off += (size_t)B * K * 4;   // counts+cursor contiguous
    int* cursor   = (int*)(ws + off);   off += (size_t)B * K * 4;
    int* order    = (int*)(ws + off);   off += (size_t)B * N * 4;
    int* inds     = (int*)(ws + off);   off += (size_t)K * 4;

    hipMemsetAsync(totsum, 0, (size_t)B * D * 4, stream);
    k_init_inds<<<1, 64, 0, stream>>>(inds);
    k_gather_v0<<<B * K, 64, 0, stream>>>(x, inds, v);
    k_rownorm<<<(B * N) / 4, 256, 0, stream>>>(x, x2, B * N);
    k_totsum<<<dim3(64, B), 256, 0, stream>>>(x, totsum);

    for (int it = 0; it < ITERS; it++) {
        k_rownorm<<<(B * K) / 4, 256, 0, stream>>>(v, v2, B * K);
        k_assign<<<dim3(N / 64, B), 256, 0, stream>>>(x, v, x2, v2, assign);
        hipMemsetAsync(counts, 0, 2 * (size_t)B * K * 4, stream);  // counts + cursor
        k_count<<<(B * N) / 256, 256, 0, stream>>>(assign, counts);
        k_scatter<<<dim3(N / 256, B), 256, 0, stream>>>(assign, counts, cursor, order);
        k_sumdiv<<<dim3(K, B), 256, 0, stream>>>(x, counts, order, totsum, v);
    }

    hipMemsetAsync(out, 0, (size_t)B * N * K * 4, stream);
    k_write_u<<<(B * N) / 256, 256, 0, stream>>>(assign, out);
    k_copy_v<<<(B * K * D) / 1024, 256, 0, stream>>>(v, out + (size_t)B * N * K);
}

// Round 2
// 2845.481 us; speedup vs baseline: 1.2499x; 1.2499x over previous
//
#include <hip/hip_runtime.h>
#include <string.h>

#define B 4
#define N 16384
#define D 256
#define K 512
#define ITERS 10

// ---------------- host MT19937 exactly matching CPython random.seed(42); random.sample(range(16384), 512)
static void host_sample_inds(int* out) {
    static unsigned int mt[624];
    mt[0] = 19650218u;
    for (int i = 1; i < 624; i++)
        mt[i] = 1812433253u * (mt[i - 1] ^ (mt[i - 1] >> 30)) + (unsigned)i;
    {
        int i = 1, j = 0;
        for (int kk = 624; kk; kk--) {
            mt[i] = (mt[i] ^ ((mt[i - 1] ^ (mt[i - 1] >> 30)) * 1664525u)) + 42u + (unsigned)j;
            i++; j++;
            if (i >= 624) { mt[0] = mt[623]; i = 1; }
            if (j >= 1) j = 0;
        }
        for (int kk = 623; kk; kk--) {
            mt[i] = (mt[i] ^ ((mt[i - 1] ^ (mt[i - 1] >> 30)) * 1566083941u)) - (unsigned)i;
            i++;
            if (i >= 624) { mt[0] = mt[623]; i = 1; }
        }
        mt[0] = 0x80000000u;
    }
    static unsigned char seen[N];
    memset(seen, 0, sizeof(seen));
    int mti = 624;
    int got = 0;
    while (got < K) {
        if (mti >= 624) {
            for (int kk = 0; kk < 624; kk++) {
                unsigned int yy = (mt[kk] & 0x80000000u) | (mt[(kk + 1) % 624] & 0x7fffffffu);
                mt[kk] = mt[(kk + 397) % 624] ^ (yy >> 1) ^ ((yy & 1u) ? 0x9908b0dfu : 0u);
            }
            mti = 0;
        }
        unsigned int y = mt[mti++];
        y ^= y >> 11; y ^= (y << 7) & 0x9d2c5680u; y ^= (y << 15) & 0xefc60000u; y ^= y >> 18;
        unsigned int r = y >> 17;          // getrandbits(15)
        if (r >= (unsigned)N) continue;    // _randbelow rejection
        if (seen[r]) continue;             // sample's duplicate rejection
        seen[r] = 1;
        out[got++] = (int)r;
    }
}

__global__ void k_gather_v0(const float* __restrict__ x, const int* __restrict__ inds,
                            float* __restrict__ v) {
    int bk = blockIdx.x; int b = bk / K, k = bk % K;
    int n = inds[k];
    const float4* src = (const float4*)(x + ((size_t)b * N + n) * D);
    float4* dst = (float4*)(v + ((size_t)b * K + k) * D);
    dst[threadIdx.x] = src[threadIdx.x];
}

// squared row norms; one wave per row (D=256 -> one float4 per lane)
__global__ void k_rownorm(const float* __restrict__ a, float* __restrict__ out, int nrows) {
    int wave = threadIdx.x >> 6;
    int lane = threadIdx.x & 63;
    int row = blockIdx.x * 4 + wave;
    if (row >= nrows) return;
    float4 f = ((const float4*)(a + (size_t)row * D))[lane];
    float s = f.x * f.x + f.y * f.y + f.z * f.z + f.w * f.w;
    #pragma unroll
    for (int off = 32; off; off >>= 1) s += __shfl_xor(s, off);
    if (lane == 0) out[row] = s;
}

// totsum[b][d] = sum_n x[b][n][d]  (fallback for empty clusters: un = eps/eps = 1.0 for all n)
__global__ void k_totsum(const float* __restrict__ x, float* __restrict__ totsum) {
    int b = blockIdx.y;
    int n0 = blockIdx.x * (N / 64);
    int t = threadIdx.x;
    const float* xb = x + (size_t)b * N * D;
    float s = 0.f;
    for (int n = n0; n < n0 + N / 64; n++) s += xb[(size_t)n * D + t];
    atomicAdd(&totsum[b * D + t], s);
}

// ---------------- assignment: fused fp32 GEMM (x . v^T) + argmin of relu(x2 - 2*dot + v2)
// 128 points x 128 centers per block, BK=32, 256 threads (16 tx x 16 ty), 8x8 microtile
// microtile rows: {ty*4+i, 64+ty*4+i}; cols: {tx*4+j, 64+tx*4+j}  -> 2-way LDS aliasing only (free)
#define LDSTRIDE 129
__global__ __launch_bounds__(256, 2) void k_assign(
    const float* __restrict__ x, const float* __restrict__ v,
    const float* __restrict__ x2, const float* __restrict__ v2,
    int* __restrict__ assign) {
    __shared__ float xs[32 * LDSTRIDE];
    __shared__ float vs[32 * LDSTRIDE];
    int b = blockIdx.y;
    int n0 = blockIdx.x * 128;
    int tid = threadIdx.x;
    int tx = tid & 15, ty = tid >> 4;
    const float* xb = x + (size_t)b * N * D;
    const float* vb = v + (size_t)b * K * D;
    const float* v2b = v2 + b * K;

    float x2p[8];
    #pragma unroll
    for (int i = 0; i < 8; i++) {
        int p = (i < 4) ? (ty * 4 + i) : (64 + ty * 4 + i - 4);
        x2p[i] = x2[b * N + n0 + p];
    }
    float minv[8]; int mini[8];
    #pragma unroll
    for (int i = 0; i < 8; i++) { minv[i] = 3.4e38f; mini[i] = 0; }

    for (int kc = 0; kc < K / 128; kc++) {
        float acc[8][8];
        #pragma unroll
        for (int i = 0; i < 8; i++)
            #pragma unroll
            for (int j = 0; j < 8; j++) acc[i][j] = 0.f;

        for (int dc = 0; dc < D / 32; dc++) {
            // coalesced global loads: idx = tid + k*256; row = idx>>3 (0..127), col4 = idx&7
            float4 xg[4], vg[4];
            #pragma unroll
            for (int k = 0; k < 4; k++) {
                int idx = tid + k * 256;
                int row = idx >> 3, col4 = idx & 7;
                xg[k] = *(const float4*)&xb[(size_t)(n0 + row) * D + dc * 32 + col4 * 4];
                vg[k] = *(const float4*)&vb[(size_t)(kc * 128 + row) * D + dc * 32 + col4 * 4];
            }
            __syncthreads();   // previous tile fully consumed
            #pragma unroll
            for (int k = 0; k < 4; k++) {
                int idx = tid + k * 256;
                int row = idx >> 3, col4 = idx & 7;
                float xa[4] = {xg[k].x, xg[k].y, xg[k].z, xg[k].w};
                float va[4] = {vg[k].x, vg[k].y, vg[k].z, vg[k].w};
                #pragma unroll
                for (int c = 0; c < 4; c++) {
                    xs[(col4 * 4 + c) * LDSTRIDE + row] = xa[c];   // bank=(4*col4+c+row)%32: 2-way
                    vs[(col4 * 4 + c) * LDSTRIDE + row] = va[c];
                }
            }
            __syncthreads();
            #pragma unroll 4
            for (int d = 0; d < 32; d++) {
                float4 xf0 = *(const float4*)&xs[d * LDSTRIDE + ty * 4];
                float4 xf1 = *(const float4*)&xs[d * LDSTRIDE + 64 + ty * 4];
                float4 vf0 = *(const float4*)&vs[d * LDSTRIDE + tx * 4];
                float4 vf1 = *(const float4*)&vs[d * LDSTRIDE + 64 + tx * 4];
                float xa[8] = {xf0.x, xf0.y, xf0.z, xf0.w, xf1.x, xf1.y, xf1.z, xf1.w};
                float va[8] = {vf0.x, vf0.y, vf0.z, vf0.w, vf1.x, vf1.y, vf1.z, vf1.w};
                #pragma unroll
                for (int i = 0; i < 8; i++)
                    #pragma unroll
                    for (int j = 0; j < 8; j++)
                        acc[i][j] = fmaf(xa[i], va[j], acc[i][j]);
            }
        }
        // epilogue for this 128-center chunk (ascending center index within each thread)
        #pragma unroll
        for (int j = 0; j < 8; j++) {
            int kk = kc * 128 + ((j < 4) ? (tx * 4 + j) : (64 + tx * 4 + j - 4));
            float v2v = v2b[kk];
            #pragma unroll
            for (int i = 0; i < 8; i++) {
                float dist = (x2p[i] - 2.0f * acc[i][j]) + v2v;  // ref expression order
                dist = fmaxf(dist, 0.0f);                        // relu
                if (dist < minv[i]) { minv[i] = dist; mini[i] = kk; }
            }
        }
    }
    // reduce (min, first-index) across the 16 tx lanes (consecutive lanes within wave)
    #pragma unroll
    for (int i = 0; i < 8; i++) {
        float mv = minv[i]; int mi = mini[i];
        #pragma unroll
        for (int off = 1; off < 16; off <<= 1) {
            float ov = __shfl_xor(mv, off);
            int oi = __shfl_xor(mi, off);
            if (ov < mv || (ov == mv && oi < mi)) { mv = ov; mi = oi; }
        }
        if (tx == 0) {
            int p = (i < 4) ? (ty * 4 + i) : (64 + ty * 4 + i - 4);
            assign[b * N + n0 + p] = mi;
        }
    }
}

__global__ void k_count(const int* __restrict__ assign, int* __restrict__ counts) {
    int idx = blockIdx.x * 256 + threadIdx.x;
    int b = idx / N;
    int a = assign[idx];
    atomicAdd(&counts[b * K + a], 1);
}

// counting-sort scatter: block = 256 consecutive points of one batch
__global__ __launch_bounds__(256) void k_scatter(
    const int* __restrict__ assign, const int* __restrict__ counts,
    int* __restrict__ cursor, int* __restrict__ order) {
    __shared__ int offs[K];
    int b = blockIdx.y;
    if (threadIdx.x < 64) {       // wave 0 computes exclusive prefix of counts[b][*]
        int lane = threadIdx.x;
        int pre[8]; int s = 0;
        #pragma unroll
        for (int j = 0; j < 8; j++) { pre[j] = s; s += counts[b * K + lane * 8 + j]; }
        int inc = s;
        #pragma unroll
        for (int off = 1; off < 64; off <<= 1) {
            int o = __shfl_up(inc, off);
            if (lane >= off) inc += o;
        }
        int excl = inc - s;
        #pragma unroll
        for (int j = 0; j < 8; j++) offs[lane * 8 + j] = excl + pre[j];
    }
    __syncthreads();
    int n = blockIdx.x * 256 + threadIdx.x;
    int a = assign[b * N + n];
    int pos = atomicAdd(&cursor[b * K + a], 1);
    order[b * N + offs[a] + pos] = n;
}

// per-(b,k): mean of member rows; empty cluster -> totsum row. thread t <-> dim t (D==256==blockDim)
__global__ __launch_bounds__(256) void k_sumdiv(
    const float* __restrict__ x, const int* __restrict__ counts,
    const int* __restrict__ order, const float* __restrict__ totsum,
    float* __restrict__ v) {
    __shared__ int sh[256];
    __shared__ int ord[256];
    int t = threadIdx.x;
    int b = blockIdx.y, k = blockIdx.x;
    const int* cb = counts + b * K;
    int partial = 0;
    for (int j = t; j < k; j += 256) partial += cb[j];
    sh[t] = partial; __syncthreads();
    for (int s = 128; s; s >>= 1) { if (t < s) sh[t] += sh[t + s]; __syncthreads(); }
    int off = sh[0];
    int cnt = cb[k];
    const float* xb = x + (size_t)b * N * D;
    float acc = 0.f;
    for (int m0 = 0; m0 < cnt; m0 += 256) {
        int mm = min(256, cnt - m0);
        if (t < mm) ord[t] = order[b * N + off + m0 + t];
        __syncthreads();
        for (int m = 0; m < mm; m++) {
            int n = ord[m];
            acc += xb[(size_t)n * D + t];
        }
        __syncthreads();
    }
    float out;
    if (cnt > 0) out = acc * (1.0f / (float)cnt);   // un_member = (1+eps)/(cnt+eps) == 1/cnt in fp32
    else out = totsum[b * D + t];                   // un = eps/eps = 1.0 for all n
    v[((size_t)b * K + k) * D + t] = out;
}

__global__ void k_write_u(const int* __restrict__ assign, float* __restrict__ uout) {
    int idx = blockIdx.x * 256 + threadIdx.x;
    int a = assign[idx];
    uout[(size_t)idx * K + a] = 1.0f;
}

__global__ void k_copy_v(const float* __restrict__ v, float* __restrict__ out) {
    int idx = blockIdx.x * 256 + threadIdx.x;
    ((float4*)out)[idx] = ((const float4*)v)[idx];
}

extern "C" void kernel_launch(void* const* d_in, const int* in_sizes, int n_in,
                              void* d_out, int out_size, void* d_ws, size_t ws_size,
                              hipStream_t stream) {
    const float* x = (const float*)d_in[0];
    float* out = (float*)d_out;
    char* ws = (char*)d_ws;
    size_t off = 0;
    float* v      = (float*)(ws + off); off += (size_t)B * K * D * 4;
    float* x2     = (float*)(ws + off); off += (size_t)B * N * 4;
    float* v2     = (float*)(ws + off); off += (size_t)B * K * 4;
    float* totsum = (float*)(ws + off); off += (size_t)B * D * 4;
    int* assign   = (int*)(ws + off);   off += (size_t)B * N * 4;
    int* counts   = (int*)(ws + off);   off += (size_t)B * K * 4;   // counts+cursor contiguous
    int* cursor   = (int*)(ws + off);   off += (size_t)B * K * 4;
    int* order    = (int*)(ws + off);   off += (size_t)B * N * 4;
    int* inds     = (int*)(ws + off);   off += (size_t)K * 4;

    static int h_inds[K];
    host_sample_inds(h_inds);   // deterministic; recomputed identically every call
    hipMemcpyAsync(inds, h_inds, K * sizeof(int), hipMemcpyHostToDevice, stream);

    hipMemsetAsync(totsum, 0, (size_t)B * D * 4, stream);
    k_gather_v0<<<B * K, 64, 0, stream>>>(x, inds, v);
    k_rownorm<<<(B * N) / 4, 256, 0, stream>>>(x, x2, B * N);
    k_totsum<<<dim3(64, B), 256, 0, stream>>>(x, totsum);

    for (int it = 0; it < ITERS; it++) {
        k_rownorm<<<(B * K) / 4, 256, 0, stream>>>(v, v2, B * K);
        k_assign<<<dim3(N / 128, B), 256, 0, stream>>>(x, v, x2, v2, assign);
        hipMemsetAsync(counts, 0, 2 * (size_t)B * K * 4, stream);  // counts + cursor
        k_count<<<(B * N) / 256, 256, 0, stream>>>(assign, counts);
        k_scatter<<<dim3(N / 256, B), 256, 0, stream>>>(assign, counts, cursor, order);
        k_sumdiv<<<dim3(K, B), 256, 0, stream>>>(x, counts, order, totsum, v);
    }

    hipMemsetAsync(out, 0, (size_t)B * N * K * 4, stream);
    k_write_u<<<(B * N) / 256, 256, 0, stream>>>(assign, out);
    k_copy_v<<<(B * K * D) / 1024, 256, 0, stream>>>(v, out + (size_t)B * N * K);
}